// Round 11
// baseline (542.139 us; speedup 1.0000x reference)
//
#include <hip/hip_runtime.h>
#include <hip/hip_bf16.h>

#define NTOT 4194304
typedef __attribute__((ext_vector_type(4)))  short short4v;
typedef __attribute__((ext_vector_type(8)))  short short8v;
typedef __attribute__((ext_vector_type(4)))  float f32x4;

__device__ __forceinline__ ushort f2bf(float f){
    __hip_bfloat16 h = __float2bfloat16(f);
    return __bfloat16_as_ushort(h);
}
__device__ __forceinline__ float bf2f(ushort u){
    return __uint_as_float(((unsigned)u)<<16);
}

// ---------------- weight pack: per-lane MFMA B-fragment order, bf16 ----------------
// dwPk[l][ciq4][kkp5][koff2][cih2][jg2][co64][j4]
// owPk[l][ciq4][kkp5][koff2][cih2][jg2][co32][j4]
__global__ __launch_bounds__(256) void pack_w(
    const float* __restrict__ dw, const float* __restrict__ ow,
    ushort* __restrict__ dwPk, ushort* __restrict__ owPk,
    float* __restrict__ statsG)
{
    int i = blockIdx.x*256 + threadIdx.x;
    if (i < 286720) {
        int j = i&3, co = (i>>2)&63, jg=(i>>8)&1, cih=(i>>9)&1, koff=(i>>10)&1;
        int r = i>>11; int kkp = r%5; int r2 = r/5; int ciq = r2&3; int l = r2>>2;
        int kk = kkp*2+koff, ci = ciq*16 + cih*8 + jg*4 + j;
        float v = (kk<9)? dw[((l*64+co)*64+ci)*9+kk] : 0.f;
        dwPk[i] = f2bf(v);
    }
    if (i < 143360) {
        int j = i&3, co = (i>>2)&31, jg=(i>>7)&1, cih=(i>>8)&1, koff=(i>>9)&1;
        int r = i>>10; int kkp = r%5; int r2 = r/5; int ciq = r2&3; int l = r2>>2;
        int kk = kkp*2+koff, ci = ciq*16 + cih*8 + jg*4 + j;
        float v = (kk<9 && co<18)? ow[((l*18+co)*64+ci)*9+kk] : 0.f;
        owPk[i] = f2bf(v);
    }
    if (i < 7*1024) statsG[i] = 0.f;   // zero stats accumulators (capture-safe)
}

// ---------------- per-layer transpose: NCHW f32 -> [b][y][x][ci] bf16 ----------------
// Block 256: one (b,y) row. Coalesced f32 reads, LDS transpose, b128 bf16 writes.
__global__ __launch_bounds__(256) void transpose_x(
    const float* __restrict__ src, ushort* __restrict__ xT)
{
    __shared__ ushort lds[128*72];   // [x 128][ci 72pad] (stride 144B = 16B-mult)
    const int bid = blockIdx.x, t = threadIdx.x;
    const int b = bid>>7, y = bid&127;
    const float* sp = src + (b<<20) + (y<<7);
#pragma unroll
    for (int i=0;i<32;i++){
        int lin = i*256 + t;                 // 8192 = 64ci x 128x
        int ci = lin>>7, xx = lin&127;
        lds[xx*72 + ci] = f2bf(sp[(ci<<14) + xx]);
    }
    __syncthreads();
    ushort* dp = xT + (((b<<7)+y)<<13);      // ((b*128+y)*128)*64
#pragma unroll
    for (int i=0;i<4;i++){
        int u = i*256 + t;                   // 1024 slots of 8 ci
        int xx = u>>3, cg = u&7;
        short8v v8 = *(const short8v*)(lds + xx*72 + cg*8);
        *(short8v*)(dp + (xx<<6) + cg*8) = v8;
    }
}

// kh/kw tables; index 9 clamps to kk=8 (ghost K-slots carry zero weights)
__constant__ int KHt[10] = {0,0,0,1,1,1,2,2,2,2};
__constant__ int KWt[10] = {0,1,2,0,1,2,0,1,2,2};

// ---------------- fused offset-conv + deformable conv, gathers from global xT ----------------
// Block: 256 thr = 4 waves; tile 4 rows x 32 cols; wave = 32 px (2 A-frags).
// Grid 512, XCD-bijective decode (half image per XCD: 1MB xT slab < 4MB L2).
// No x LDS tile: corners gathered as b128 from channel-last xT (exact reference
// semantics -- clamped coords always valid, validity via zero weights; no fallback).
// LDS 18.9KB (offsets + epilogue) -> occupancy VGPR-bound (~4 waves/SIMD), the
// whole point: rounds 8-10 were stuck at 2 waves/SIMD behind a 143KB tile.
// A-frag lane: pixel = p*16+(lane&15); k-slot: kk=2kkp+(lane>>5), ci=ciq*16+8*((lane>>4)&1)+j.
// C/D: col=lane&15 (co), row=(lane>>4)*4+reg (pix).
__global__ __attribute__((amdgpu_flat_work_group_size(256,256)))
void dcn_layer(
    const ushort* __restrict__ xT, const ushort* __restrict__ owPk,
    const float* __restrict__ ob, const ushort* __restrict__ dwPk,
    ushort* __restrict__ yb, float* __restrict__ statsL)
{
    __shared__ __align__(16) char smem[18944];
    float* offl = (float*)smem;              // [128 pix][20] f32 = 10240 B

    const int t = threadIdx.x, lane = t&63, w = t>>6;
    const int l15 = lane&15, lg = lane>>4;
    const int cih = lg&1, koff = lane>>5;
    const int bid = blockIdx.x;
    const int xcd = bid&7, idx = bid>>3;
    const int b = xcd>>1, vh = xcd&1;
    const int ht = vh*16 + (idx>>2), wt = idx&3;
    const int w0 = wt*32, h0 = ht*4;
    const int row = h0 + w;
    const ushort* xb = xT + (b<<20);         // batch slab

    // ================= pass 1: offset conv via MFMA (A from xT) =================
    f32x4 oacc[2][2];
#pragma unroll
    for (int p=0;p<2;p++)
#pragma unroll
        for (int q=0;q<2;q++) oacc[p][q] = (f32x4){0.f,0.f,0.f,0.f};

#pragma unroll 1
    for (int kkp=0; kkp<5; ++kkp) {
        int kkA = 2*kkp;
        int kkB = (kkA+1>8)?8:(kkA+1);
        int kh = koff ? KHt[kkB] : KHt[kkA];
        int kw = koff ? KWt[kkB] : KWt[kkA];
        int gy = row + kh - 1;
        bool vy = ((unsigned)gy<128u);
        int gyc = min(max(gy,0),127);
        int ebase[2]; bool okp[2];
#pragma unroll
        for (int p=0;p<2;p++){
            int gx = w0 + p*16 + l15 + kw - 1;
            okp[p] = vy && ((unsigned)gx<128u);
            int gxc = min(max(gx,0),127);
            ebase[p] = (((gyc<<7)+gxc)<<6) + cih*8;
        }
        const short8v zz = (short8v){0,0,0,0,0,0,0,0};
#pragma unroll
        for (int ciq=0; ciq<4; ++ciq) {
            short8v afr[2];
#pragma unroll
            for (int p=0;p<2;p++){
                short8v q = *(const short8v*)(xb + ebase[p] + ciq*16);
                afr[p] = okp[p] ? q : zz;
            }
            const ushort* wop = owPk + ciq*5120 + kkp*1024 + koff*512 + cih*256;
#pragma unroll
            for (int q=0;q<2;q++){
                short4v b0 = *(const short4v*)(wop +       (q*16+l15)*4);
                short4v b1 = *(const short4v*)(wop + 128 + (q*16+l15)*4);
                short8v bb = __builtin_shufflevector(b0,b1,0,1,2,3,4,5,6,7);
#pragma unroll
                for (int p=0;p<2;p++)
                    oacc[p][q] = __builtin_amdgcn_mfma_f32_16x16x32_bf16(afr[p], bb, oacc[p][q], 0,0,0);
            }
        }
    }

    // redistribute offsets: offl[pix 128][20]; only o<18 (stride-20 overflow guard)
    float biasq[2];
#pragma unroll
    for (int q=0;q<2;q++){ int o = q*16+l15; biasq[q] = (o<18)? ob[o] : 0.f; }
#pragma unroll
    for (int p=0;p<2;p++)
#pragma unroll
        for (int q=0;q<2;q++){
            int o = q*16+l15;
            if (o < 18) {
#pragma unroll
                for (int r=0;r<4;r++){
                    int pix = w*32 + p*16 + lg*4 + r;
                    offl[pix*20 + o] = oacc[p][q][r] + biasq[q];
                }
            }
        }
    __syncthreads();

    // ================= pass 2: deformable conv via MFMA (corners from xT) =================
    f32x4 acc[2][4];
#pragma unroll
    for (int p=0;p<2;p++)
#pragma unroll
        for (int q=0;q<4;q++) acc[p][q] = (f32x4){0.f,0.f,0.f,0.f};

#pragma unroll 1
    for (int kkp=0; kkp<5; ++kkp) {
        int kkA = 2*kkp;
        int kkB = (kkA+1>8)?8:(kkA+1);
        int kh = koff ? KHt[kkB] : KHt[kkA];
        int kw = koff ? KWt[kkB] : KWt[kkA];
        int kkX = koff ? kkB : kkA;

        // hoisted (ciq-invariant) bilinear per A-frag: weights + corner bases
        float f00a[2],f01a[2],f10a[2],f11a[2];
        int e00a[2],e01a[2],e10a[2],e11a[2];
#pragma unroll
        for (int p=0;p<2;p++){
            int pix = w*32 + p*16 + l15;
            float2 od = *(const float2*)(offl + pix*20 + 2*kkX);
            float py = (float)(row + kh - 1) + od.x;
            float px = (float)(w0 + p*16 + l15 + kw - 1) + od.y;
            float fy = floorf(py), fx = floorf(px);
            float ly = py - fy, lx = px - fx;
            int y0 = (int)fy, x0 = (int)fx;
            int y1 = y0+1, x1 = x0+1;
            bool vy0 = ((unsigned)y0<128u), vy1 = ((unsigned)y1<128u);
            bool vx0 = ((unsigned)x0<128u), vx1 = ((unsigned)x1<128u);
            int y0c = min(max(y0,0),127), y1c = min(max(y1,0),127);
            int x0c = min(max(x0,0),127), x1c = min(max(x1,0),127);
            f00a[p] = (vy0&&vx0) ? (1.f-ly)*(1.f-lx) : 0.f;
            f01a[p] = (vy0&&vx1) ? (1.f-ly)*lx       : 0.f;
            f10a[p] = (vy1&&vx0) ? ly*(1.f-lx)       : 0.f;
            f11a[p] = (vy1&&vx1) ? ly*lx             : 0.f;
            e00a[p] = (((y0c<<7)+x0c)<<6) + cih*8;
            e01a[p] = (((y0c<<7)+x1c)<<6) + cih*8;
            e10a[p] = (((y1c<<7)+x0c)<<6) + cih*8;
            e11a[p] = (((y1c<<7)+x1c)<<6) + cih*8;
        }

#pragma unroll
        for (int ciq=0; ciq<4; ++ciq) {
            short8v afr[2];
#pragma unroll
            for (int p=0;p<2;p++){
                short8v q00 = *(const short8v*)(xb + e00a[p] + ciq*16);
                short8v q01 = *(const short8v*)(xb + e01a[p] + ciq*16);
                short8v q10 = *(const short8v*)(xb + e10a[p] + ciq*16);
                short8v q11 = *(const short8v*)(xb + e11a[p] + ciq*16);
                float sv[8];
#pragma unroll
                for (int j=0;j<8;j++)
                    sv[j] = f00a[p]*bf2f((ushort)q00[j]) + f01a[p]*bf2f((ushort)q01[j])
                          + f10a[p]*bf2f((ushort)q10[j]) + f11a[p]*bf2f((ushort)q11[j]);
#pragma unroll
                for (int j=0;j<8;j++) afr[p][j] = (short)f2bf(sv[j]);
            }
            const ushort* wp = dwPk + ciq*10240 + kkp*2048 + koff*1024 + cih*512;
#pragma unroll
            for (int q=0;q<4;q++){
                short4v b0 = *(const short4v*)(wp +       (q*16+l15)*4);
                short4v b1 = *(const short4v*)(wp + 256 + (q*16+l15)*4);
                short8v bb = __builtin_shufflevector(b0,b1,0,1,2,3,4,5,6,7);
                acc[0][q] = __builtin_amdgcn_mfma_f32_16x16x32_bf16(afr[0], bb, acc[0][q], 0,0,0);
                acc[1][q] = __builtin_amdgcn_mfma_f32_16x16x32_bf16(afr[1], bb, acc[1][q], 0,0,0);
            }
        }
    }

    // ================= epilogue: LDS transpose, bf16 store, stats =================
    float* yt  = (float*)smem;               // [32 co][132] f32 = 16896 B (overlays offl)
    float* red = (float*)(smem + 16896);     // 512 f32
#pragma unroll
    for (int half=0; half<2; ++half){
        __syncthreads();   // half0: offl reads done; half1: prev stats reads done
#pragma unroll
        for (int p=0;p<2;p++)
#pragma unroll
            for (int qq=0;qq<2;qq++)
                *(f32x4*)(yt + (qq*16+l15)*132 + w*32 + p*16 + lg*4) = acc[p][half*2+qq];
        __syncthreads();
#pragma unroll
        for (int i=0;i<2;i++){
            int u = i*256 + t;                   // 512 slots of 8 px
            int co = u>>4, pxg = (u&15)*8;
            short8v v8;
#pragma unroll
            for (int e=0;e<8;e++) v8[e] = (short)f2bf(yt[co*132 + pxg + e]);
            *(short8v*)(yb + ((((b<<6) + half*32 + co)<<14)
                        + ((h0 + (pxg>>5))<<7) + w0 + (pxg&31))) = v8;
        }
        {
            float s=0.f, s2=0.f;
            int co = t&31, seg = t>>5;           // 8 segs x 16 px
            const float* bp = yt + co*132 + seg*16;
#pragma unroll
            for (int qd=0;qd<16;qd++){ float v = bp[qd]; s += v; s2 += v*v; }
            red[seg*32+co] = s; red[256 + seg*32+co] = s2;
        }
        __syncthreads();
        if (t < 64){
            int vv = t>>5, cc = t&31;
            float a = 0.f;
#pragma unroll
            for (int g=0;g<8;g++) a += red[vv*256 + g*32 + cc];
            atomicAdd(statsL + (bid&7)*128 + vv*64 + half*32 + cc, a);
        }
    }
}

// ---------------- normalize + ReLU + epilogue (yb is bf16) ----------------
// mode 0: out = relu(.)   mode 1: out = relu(.) + addsrc   mode 2: out += relu(.)
__global__ __launch_bounds__(256) void norm2(
    const ushort* __restrict__ yv, const float* __restrict__ statsL,
    const float* __restrict__ gamma, const float* __restrict__ beta,
    const float* __restrict__ addsrc, float* out, int mode)
{
    const int i8 = blockIdx.x*256 + threadIdx.x;   // 524288 total, 8 elems each
    const int ch = (i8 >> 11) & 63;
    float sum=0.f, ssq=0.f;
#pragma unroll
    for (int s=0;s<8;s++){ sum += statsL[s*128+ch]; ssq += statsL[s*128+64+ch]; }
    float mean = sum*(1.f/65536.f);
    float var  = ssq*(1.f/65536.f) - mean*mean;
    float inv  = rsqrtf(var + 1e-5f);
    float sc = gamma[ch]*inv, sh = beta[ch] - mean*sc;
    short8v v8 = *(const short8v*)(yv + i8*8);
    float r[8];
#pragma unroll
    for (int e=0;e<8;e++) r[e] = fmaxf(bf2f((ushort)v8[e])*sc+sh, 0.f);
    if (mode == 1) {
        const float4* ap = (const float4*)(addsrc + i8*8);
        float4 a0 = ap[0], a1 = ap[1];
        r[0]+=a0.x; r[1]+=a0.y; r[2]+=a0.z; r[3]+=a0.w;
        r[4]+=a1.x; r[5]+=a1.y; r[6]+=a1.z; r[7]+=a1.w;
    } else if (mode == 2) {
        const float4* op = (const float4*)(out + i8*8);
        float4 a0 = op[0], a1 = op[1];
        r[0]+=a0.x; r[1]+=a0.y; r[2]+=a0.z; r[3]+=a0.w;
        r[4]+=a1.x; r[5]+=a1.y; r[6]+=a1.z; r[7]+=a1.w;
    }
    float4* dp = (float4*)(out + i8*8);
    dp[0] = make_float4(r[0],r[1],r[2],r[3]);
    dp[1] = make_float4(r[4],r[5],r[6],r[7]);
}

// ---------------- host orchestration ----------------
extern "C" void kernel_launch(void* const* d_in, const int* in_sizes, int n_in,
                              void* d_out, int out_size, void* d_ws, size_t ws_size,
                              hipStream_t stream)
{
    const float* x  = (const float*)d_in[0];
    const float* ow = (const float*)d_in[1];
    const float* ob = (const float*)d_in[2];
    const float* dw = (const float*)d_in[3];
    const float* g  = (const float*)d_in[4];
    const float* be = (const float*)d_in[5];
    float* out = (float*)d_out;

    float*  P      = (float*)d_ws;
    float*  Q      = P + NTOT;
    ushort* ybBf   = (ushort*)(Q + NTOT);
    ushort* xT     = ybBf + NTOT;
    float*  statsG = (float*)(xT + NTOT);    // 7*1024 f32
    ushort* dwPk   = (ushort*)(statsG + 7*1024);
    ushort* owPk   = dwPk + 286720;

    pack_w<<<1120, 256, 0, stream>>>(dw, ow, dwPk, owPk, statsG);

    auto L = [&](int l, const float* in, float* dst, int mode, const float* adds){
        transpose_x<<<512, 256, 0, stream>>>(in, xT);
        dcn_layer<<<512, 256, 0, stream>>>(xT, owPk + l*20480, ob + l*18,
                                           dwPk + l*40960, ybBf, statsG + l*1024);
        norm2<<<2048, 256, 0, stream>>>(ybBf, statsG + l*1024, g + l*64, be + l*64,
                                        adds, dst, mode);
    };

    L(0, x, P,   0, nullptr);   // P = L0(x)
    L(1, P, P,   0, nullptr);   // P = L1(P)            (out_1)
    L(4, x, Q,   1, P);         // Q = L4(x) + P        (out_sum_1)
    L(2, Q, P,   0, nullptr);   // P = L2(Q)
    L(3, P, out, 0, nullptr);   // out = L3(P)
    L(5, Q, out, 2, nullptr);   // out += L5(Q)
    L(6, Q, out, 2, nullptr);   // out += L6(Q)
}